// Round 11
// baseline (166.057 us; speedup 1.0000x reference)
//
#include <hip/hip_runtime.h>

// Problem constants (from reference setup_inputs)
#define L_DIM 12
#define B_DIM 8
#define H_DIM 12
#define S2    147456              // 384*384
#define M_DIM 32
#define NL 3
#define NH 4
#define HS2   (H_DIM * S2)        // batch stride in attn elements

// design: global->register plane streaming, no LDS staging, no barriers
#define C      128                // st elements per block (chunk)
#define NCH    (S2 / C)           // 1152 blocks
#define RED1   32                 // chunks per red1 block
#define NRED1  (NCH / RED1)       // 36

#define PART_FLOATS (NCH * 256)
#define MID_FLOATS  (NRED1 * 256)
#define META_INTS   2048
// mi layout: [0]=np ; [8..168) plane base elem offsets (padded/clamped) ;
//            [168..168+1176) weight bytes packed 4 m/int, 8 ints/plane (zero padded)

// ---------------- setup: parallel, LDS-only (proven ~µs in R7/R8) ----------------
__global__ __launch_bounds__(256) void pfe_setup(
    const int* __restrict__ lidx, const int* __restrict__ hidx, int* __restrict__ mi)
{
    __shared__ unsigned char s_cl[M_DIM][16];
    __shared__ unsigned char s_ch[M_DIM][16];
    __shared__ int s_used[144];
    __shared__ int s_slot[144];
    const int t = threadIdx.x;
    for (int i = t; i < 1176; i += 256) mi[168 + i] = 0;   // zero weight region
    if (t < M_DIM) {
        for (int l = 0; l < L_DIM; ++l) s_cl[t][l] = 0;
        for (int h = 0; h < H_DIM; ++h) s_ch[t][h] = 0;
        for (int i = 0; i < NL; ++i) s_cl[t][lidx[t * NL + i]]++;
        for (int j = 0; j < NH; ++j) s_ch[t][hidx[t * NH + j]]++;
    }
    __syncthreads();
    if (t < 144) {
        const int l = t / H_DIM, h = t % H_DIM;
        int u = 0;
        for (int m = 0; m < M_DIM; ++m) u |= (s_cl[m][l] && s_ch[m][h]) ? 1 : 0;
        s_used[t] = u;
    }
    __syncthreads();
    if (t == 0) {
        int np = 0, lastb = 0;
        for (int k = 0; k < 144; ++k) {
            if (s_used[k]) {
                s_slot[k] = np;
                lastb = ((k / H_DIM) * (B_DIM * H_DIM) + (k % H_DIM)) * S2;
                mi[8 + np] = lastb;
                ++np;
            } else s_slot[k] = -1;
        }
        for (int p = np; p < 160; ++p) mi[8 + p] = lastb;   // clamp pads (safe loads)
        mi[0] = np;
    }
    __syncthreads();
    if (t < 144) {
        const int sl = s_slot[t];
        if (sl >= 0) {
            const int l = t / H_DIM, h = t % H_DIM;
            int wd[8] = {0, 0, 0, 0, 0, 0, 0, 0};
#pragma unroll
            for (int g = 0; g < 8; ++g) {
                int w = 0;
#pragma unroll
                for (int j = 0; j < 4; ++j) {
                    const int m = g * 4 + j;
                    w |= ((int)s_cl[m][l] * (int)s_ch[m][h]) << (8 * j);
                }
                wd[g] = w;
            }
            int* wp = mi + 168 + sl * 8;
#pragma unroll
            for (int g = 0; g < 8; ++g) wp[g] = wd[g];
        }
    }
}

// ---------------- main: global->register streaming, register scatter ----------
// 256 threads = 4 waves. thread = (b = t>>5, q = t&31) owns float4 at st=q*4.
// acc[32] float4 in VGPRs (ALL indices compile-time static — R9 showed that
// losing this demotes acc to scratch for a 6x slowdown). No barriers in the
// gather loop. NEW in R11: each block starts its plane sweep at a staggered
// offset (wraparound) so chip-wide DRAM demand spreads over all 1032
// (plane,b) rows instead of a moving hot band.
__global__ __launch_bounds__(256) void pfe_gather(
    const float* __restrict__ attn, const float* __restrict__ refs,
    const int* __restrict__ mi, float* __restrict__ part)
{
    __shared__ int s_pbase[160];
    __shared__ int s_ww[1176];
    __shared__ float s_x[8 * B_DIM * C];   // 32 KB exchange (8 m-slice)

    const int t = threadIdx.x;
    for (int i = t; i < 160; i += 256) s_pbase[i] = mi[8 + i];
    for (int i = t; i < 1176; i += 256) s_ww[i] = mi[168 + i];
    const int np4 = (mi[0] + 3) & ~3;
    __syncthreads();

    const int b = t >> 5, q = t & 31;
    const unsigned off0 = (unsigned)blockIdx.x * C;
    const unsigned fixoff = (unsigned)b * (unsigned)HS2 + off0 + (unsigned)q * 4u;

    // staggered start (multiple of 4 keeps the 4-unroll pipeline aligned)
    const int start4 = (int)((unsigned)blockIdx.x % (unsigned)(np4 >> 2)) << 2;

    float4 acc[M_DIM];
#pragma unroll
    for (int m = 0; m < M_DIM; ++m) acc[m] = make_float4(0.f, 0.f, 0.f, 0.f);

// rotated plane index: valid for raw < 2*np4
#define ROT(RAW) ((RAW) >= np4 ? (RAW) - np4 : (RAW))
#define LD(P) (*reinterpret_cast<const float4*>(attn + (unsigned)s_pbase[P] + fixoff))

#define PROC_WORD(SW, G, V)                                             \
    if (SW) {                                                           \
        const float f0 = (float)((SW) & 255);                           \
        const float f1 = (float)(((SW) >> 8) & 255);                    \
        const float f2 = (float)(((SW) >> 16) & 255);                   \
        const float f3 = (float)(((SW) >> 24) & 255);                   \
        acc[4*(G)+0].x = fmaf(f0, (V).x, acc[4*(G)+0].x);               \
        acc[4*(G)+0].y = fmaf(f0, (V).y, acc[4*(G)+0].y);               \
        acc[4*(G)+0].z = fmaf(f0, (V).z, acc[4*(G)+0].z);               \
        acc[4*(G)+0].w = fmaf(f0, (V).w, acc[4*(G)+0].w);               \
        acc[4*(G)+1].x = fmaf(f1, (V).x, acc[4*(G)+1].x);               \
        acc[4*(G)+1].y = fmaf(f1, (V).y, acc[4*(G)+1].y);               \
        acc[4*(G)+1].z = fmaf(f1, (V).z, acc[4*(G)+1].z);               \
        acc[4*(G)+1].w = fmaf(f1, (V).w, acc[4*(G)+1].w);               \
        acc[4*(G)+2].x = fmaf(f2, (V).x, acc[4*(G)+2].x);               \
        acc[4*(G)+2].y = fmaf(f2, (V).y, acc[4*(G)+2].y);               \
        acc[4*(G)+2].z = fmaf(f2, (V).z, acc[4*(G)+2].z);               \
        acc[4*(G)+2].w = fmaf(f2, (V).w, acc[4*(G)+2].w);               \
        acc[4*(G)+3].x = fmaf(f3, (V).x, acc[4*(G)+3].x);               \
        acc[4*(G)+3].y = fmaf(f3, (V).y, acc[4*(G)+3].y);               \
        acc[4*(G)+3].z = fmaf(f3, (V).z, acc[4*(G)+3].z);               \
        acc[4*(G)+3].w = fmaf(f3, (V).w, acc[4*(G)+3].w);               \
    }

#define PROC_PLANE(RP, V)                                               \
    {                                                                   \
        const int4 wa = *reinterpret_cast<const int4*>(s_ww + (RP) * 8); \
        const int4 wb = *reinterpret_cast<const int4*>(s_ww + (RP) * 8 + 4); \
        const int w0 = __builtin_amdgcn_readfirstlane(wa.x);            \
        const int w1 = __builtin_amdgcn_readfirstlane(wa.y);            \
        const int w2 = __builtin_amdgcn_readfirstlane(wa.z);            \
        const int w3 = __builtin_amdgcn_readfirstlane(wa.w);            \
        const int w4 = __builtin_amdgcn_readfirstlane(wb.x);            \
        const int w5 = __builtin_amdgcn_readfirstlane(wb.y);            \
        const int w6 = __builtin_amdgcn_readfirstlane(wb.z);            \
        const int w7 = __builtin_amdgcn_readfirstlane(wb.w);            \
        PROC_WORD(w0, 0, V) PROC_WORD(w1, 1, V)                         \
        PROC_WORD(w2, 2, V) PROC_WORD(w3, 3, V)                         \
        PROC_WORD(w4, 4, V) PROC_WORD(w5, 5, V)                         \
        PROC_WORD(w6, 6, V) PROC_WORD(w7, 7, V)                         \
    }

    // 4-deep register prefetch pipeline over rotated plane order
    float4 n0 = LD(ROT(start4 + 0)), n1 = LD(ROT(start4 + 1)),
           n2 = LD(ROT(start4 + 2)), n3 = LD(ROT(start4 + 3));
    for (int p = 0; p < np4; p += 4) {
        const float4 c0 = n0, c1 = n1, c2 = n2, c3 = n3;
        const int f4 = ROT(p + 4 + start4), f5 = ROT(p + 5 + start4),
                  f6 = ROT(p + 6 + start4), f7 = ROT(p + 7 + start4);
        n0 = LD(f4); n1 = LD(f5); n2 = LD(f6); n3 = LD(f7);
        const int r0 = ROT(p + 0 + start4), r1 = ROT(p + 1 + start4),
                  r2 = ROT(p + 2 + start4), r3 = ROT(p + 3 + start4);
        PROC_PLANE(r0, c0)
        PROC_PLANE(r1, c1)
        PROC_PLANE(r2, c2)
        PROC_PLANE(r3, c3)
    }
#undef PROC_PLANE
#undef PROC_WORD
#undef LD
#undef ROT

    const float c12 = 1.0f / 12.0f;
    const int mm = t >> 5;   // 0..7 within slice (half-wave uniform)

    // refs prefetch for slice 0 (issued while final plane loads drain)
    float4 rv_next = *reinterpret_cast<const float4*>(
        refs + (size_t)mm * S2 + off0 + (unsigned)q * 4u);

    // ---- stats: 4 slices of 8 m's through 32 KB LDS exchange ----
#pragma unroll
    for (int sl = 0; sl < 4; ++sl) {
        __syncthreads();   // previous slice's reads done
#pragma unroll
        for (int k = 0; k < 8; ++k) {
            const float4 a = acc[sl * 8 + k];
            float4 p;
            p.x = a.x * c12; p.y = a.y * c12; p.z = a.z * c12; p.w = a.w * c12;
            *reinterpret_cast<float4*>(&s_x[(k * B_DIM + b) * C + q * 4]) = p;
        }
        __syncthreads();   // slice data ready

        const int m = sl * 8 + mm;
        const float4 rv = rv_next;
        if (sl < 3) {
            rv_next = *reinterpret_cast<const float4*>(
                refs + (size_t)(m + 8) * S2 + off0 + (unsigned)q * 4u);
        }
        float4 x[B_DIM];
#pragma unroll
        for (int bb = 0; bb < B_DIM; ++bb)
            x[bb] = *reinterpret_cast<const float4*>(&s_x[(mm * B_DIM + bb) * C + q * 4]);
        float4 mu = make_float4(0.f, 0.f, 0.f, 0.f);
#pragma unroll
        for (int bb = 0; bb < B_DIM; ++bb) {
            mu.x += x[bb].x; mu.y += x[bb].y; mu.z += x[bb].z; mu.w += x[bb].w;
        }
        mu.x *= 0.125f; mu.y *= 0.125f; mu.z *= 0.125f; mu.w *= 0.125f;
        float4 ss = make_float4(0.f, 0.f, 0.f, 0.f);
#pragma unroll
        for (int bb = 0; bb < B_DIM; ++bb) {
            const float dx = x[bb].x - mu.x, dy = x[bb].y - mu.y,
                        dz = x[bb].z - mu.z, dw = x[bb].w - mu.w;
            ss.x = fmaf(dx, dx, ss.x); ss.y = fmaf(dy, dy, ss.y);
            ss.z = fmaf(dz, dz, ss.z); ss.w = fmaf(dw, dw, ss.w);
        }
        const float c7 = 1.0f / 7.0f;
        float4 inv;
        inv.x = 1.0f / fmaxf(sqrtf(ss.x * c7), 1e-8f);
        inv.y = 1.0f / fmaxf(sqrtf(ss.y * c7), 1e-8f);
        inv.z = 1.0f / fmaxf(sqrtf(ss.z * c7), 1e-8f);
        inv.w = 1.0f / fmaxf(sqrtf(ss.w * c7), 1e-8f);

        float zs[B_DIM];
#pragma unroll
        for (int bb = 0; bb < B_DIM; ++bb) {
            const float zx = (x[bb].x - rv.x) * inv.x;
            const float zy = (x[bb].y - rv.y) * inv.y;
            const float zz = (x[bb].z - rv.z) * inv.z;
            const float zw = (x[bb].w - rv.w) * inv.w;
            zs[bb] = fmaf(zx, zx, fmaf(zy, zy, fmaf(zz, zz, zw * zw)));
        }
        // reduce over q (lane bits 0..4, stays within 32-lane half-wave)
#pragma unroll
        for (int bb = 0; bb < B_DIM; ++bb) {
            float v = zs[bb];
            v += __shfl_xor(v, 1);
            v += __shfl_xor(v, 2);
            v += __shfl_xor(v, 4);
            v += __shfl_xor(v, 8);
            v += __shfl_xor(v, 16);
            zs[bb] = v;
        }
        if (q == 0) {
            float* pp = part + blockIdx.x * 256 + m * B_DIM;
            *reinterpret_cast<float4*>(pp) =
                make_float4(zs[0], zs[1], zs[2], zs[3]);
            *reinterpret_cast<float4*>(pp + 4) =
                make_float4(zs[4], zs[5], zs[6], zs[7]);
        }
    }
}

// ---------------- deterministic two-stage reduction ----------------
__global__ __launch_bounds__(256) void pfe_red1(
    const float* __restrict__ part, float* __restrict__ mid)
{
    const int t = threadIdx.x;
    const int c0 = blockIdx.x * RED1;
    float s = 0.f;
#pragma unroll
    for (int i = 0; i < RED1; ++i) s += part[(c0 + i) * 256 + t];
    mid[blockIdx.x * 256 + t] = s;
}

__global__ __launch_bounds__(256) void pfe_red2(
    const float* __restrict__ mid, float* __restrict__ out)
{
    const int t = threadIdx.x;          // t = m*8 + b
    float s = 0.f;
#pragma unroll
    for (int i = 0; i < NRED1; ++i) s += mid[i * 256 + t];
    out[(t & 7) * M_DIM + (t >> 3)] = s * (1.0f / (float)S2);
}

// ---------------- fallback path (tiny ws): per-(m,chunk) atomic ----------------
__global__ void pfe_zero(float* __restrict__ out) {
    if (threadIdx.x < M_DIM * B_DIM) out[threadIdx.x] = 0.f;
}

#define FCH 512
#define FNCH (S2 / FCH)
__global__ __launch_bounds__(128) void pfe_fallback(
    const float* __restrict__ attn, const float* __restrict__ refs,
    const int* __restrict__ lidx, const int* __restrict__ hidx,
    float* __restrict__ out)
{
    const int p = blockIdx.x;
    const int m = p & (M_DIM - 1);
    const int chunk = p >> 5;
    const int tid = threadIdx.x;
    const unsigned st = (unsigned)chunk * FCH + (unsigned)tid * 4;

    __shared__ int   s_mk[NL * NH];
    __shared__ float s_mw[NL * NH];
    __shared__ int   s_nm;
    __shared__ float s_red[2 * B_DIM];

    if (tid == 0) {
        int keys[NL * NH];
        for (int i = 0; i < NL; ++i) {
            const int l = lidx[m * NL + i];
            for (int j = 0; j < NH; ++j) keys[i * NH + j] = l * 16 + hidx[m * NH + j];
        }
        for (int i = 1; i < NL * NH; ++i) {
            const int k = keys[i]; int j = i - 1;
            for (; j >= 0 && keys[j] > k; --j) keys[j + 1] = keys[j];
            keys[j + 1] = k;
        }
        int nm = 0;
        for (int i = 0; i < NL * NH; ++i) {
            if (nm > 0 && s_mk[nm - 1] == keys[i]) s_mw[nm - 1] += 1.0f;
            else { s_mk[nm] = keys[i]; s_mw[nm] = 1.0f; ++nm; }
        }
        s_nm = nm;
    }
    __syncthreads();

    const float4 r = *reinterpret_cast<const float4*>(refs + (unsigned)m * (unsigned)S2 + st);
    float4 acc[B_DIM];
    for (int bb = 0; bb < B_DIM; ++bb) acc[bb] = make_float4(0.f, 0.f, 0.f, 0.f);
    const int nm = s_nm;
    for (int e = 0; e < nm; ++e) {
        const int k = s_mk[e]; const float w = s_mw[e];
        const int l = k >> 4, h = k & 15;
        const unsigned base = (unsigned)(l * (B_DIM * H_DIM) + h) * (unsigned)S2 + st;
        for (int bb = 0; bb < B_DIM; ++bb) {
            const float4 v = *reinterpret_cast<const float4*>(
                attn + base + (unsigned)bb * (unsigned)HS2);
            acc[bb].x = fmaf(w, v.x, acc[bb].x); acc[bb].y = fmaf(w, v.y, acc[bb].y);
            acc[bb].z = fmaf(w, v.z, acc[bb].z); acc[bb].w = fmaf(w, v.w, acc[bb].w);
        }
    }
    const float c12 = 1.0f / 12.0f;
    float4 pmv[B_DIM];
    for (int bb = 0; bb < B_DIM; ++bb) {
        pmv[bb].x = acc[bb].x * c12; pmv[bb].y = acc[bb].y * c12;
        pmv[bb].z = acc[bb].z * c12; pmv[bb].w = acc[bb].w * c12;
    }
    float4 mu = make_float4(0.f, 0.f, 0.f, 0.f);
    for (int bb = 0; bb < B_DIM; ++bb) {
        mu.x += pmv[bb].x; mu.y += pmv[bb].y; mu.z += pmv[bb].z; mu.w += pmv[bb].w;
    }
    mu.x *= 0.125f; mu.y *= 0.125f; mu.z *= 0.125f; mu.w *= 0.125f;
    float4 ss = make_float4(0.f, 0.f, 0.f, 0.f);
    for (int bb = 0; bb < B_DIM; ++bb) {
        const float dx = pmv[bb].x - mu.x, dy = pmv[bb].y - mu.y,
                    dz = pmv[bb].z - mu.z, dw = pmv[bb].w - mu.w;
        ss.x += dx * dx; ss.y += dy * dy; ss.z += dz * dz; ss.w += dw * dw;
    }
    const float c7 = 1.0f / 7.0f;
    float4 inv;
    inv.x = 1.0f / fmaxf(sqrtf(ss.x * c7), 1e-8f);
    inv.y = 1.0f / fmaxf(sqrtf(ss.y * c7), 1e-8f);
    inv.z = 1.0f / fmaxf(sqrtf(ss.z * c7), 1e-8f);
    inv.w = 1.0f / fmaxf(sqrtf(ss.w * c7), 1e-8f);
    float s[B_DIM];
    for (int bb = 0; bb < B_DIM; ++bb) {
        const float zx = (pmv[bb].x - r.x) * inv.x;
        const float zy = (pmv[bb].y - r.y) * inv.y;
        const float zz = (pmv[bb].z - r.z) * inv.z;
        const float zw = (pmv[bb].w - r.w) * inv.w;
        s[bb] = zx * zx + zy * zy + zz * zz + zw * zw;
    }
    for (int bb = 0; bb < B_DIM; ++bb) {
        float v = s[bb];
        for (int off = 32; off > 0; off >>= 1) v += __shfl_down(v, off);
        s[bb] = v;
    }
    const int lane = tid & 63, wave = tid >> 6;
    if (lane == 0) for (int bb = 0; bb < B_DIM; ++bb) s_red[wave * B_DIM + bb] = s[bb];
    __syncthreads();
    if (tid < B_DIM) {
        const float tot = (s_red[tid] + s_red[B_DIM + tid]) * (1.0f / (float)S2);
        atomicAdd(&out[tid * M_DIM + m], tot);
    }
}

extern "C" void kernel_launch(void* const* d_in, const int* in_sizes, int n_in,
                              void* d_out, int out_size, void* d_ws, size_t ws_size,
                              hipStream_t stream) {
    const float* attn = (const float*)d_in[0];
    const float* refs = (const float*)d_in[1];
    const int*   lidx = (const int*)d_in[2];
    const int*   hidx = (const int*)d_in[3];
    float* out = (float*)d_out;

    const size_t ws_needed =
        (size_t)(PART_FLOATS + MID_FLOATS + META_INTS) * sizeof(float);

    if (ws_size >= ws_needed) {
        float* part = (float*)d_ws;
        float* mid  = part + PART_FLOATS;
        int*   mi   = (int*)(mid + MID_FLOATS);
        pfe_setup<<<1, 256, 0, stream>>>(lidx, hidx, mi);
        pfe_gather<<<NCH, 256, 0, stream>>>(attn, refs, mi, part);
        pfe_red1<<<NRED1, 256, 0, stream>>>(part, mid);
        pfe_red2<<<1, 256, 0, stream>>>(mid, out);
    } else {
        pfe_zero<<<1, 256, 0, stream>>>(out);
        pfe_fallback<<<FNCH * M_DIM, 128, 0, stream>>>(attn, refs, lidx, hidx, out);
    }
}

// Round 12
// 165.316 us; speedup vs baseline: 1.0045x; 1.0045x over previous
//
#include <hip/hip_runtime.h>

// Problem constants (from reference setup_inputs)
#define L_DIM 12
#define B_DIM 8
#define H_DIM 12
#define S2    147456              // 384*384
#define M_DIM 32
#define NL 3
#define NH 4
#define HS2   (H_DIM * S2)        // batch stride in attn elements

// design: global->register plane streaming; 512 thr, float2/thread so VGPR
// fits 128 -> 16 waves/CU (R12 probe: outstanding-miss concurrency)
#define C      128                // st elements per block (chunk)
#define NCH    (S2 / C)           // 1152 blocks
#define RED1   32                 // chunks per red1 block
#define NRED1  (NCH / RED1)       // 36

#define PART_FLOATS (NCH * 256)
#define MID_FLOATS  (NRED1 * 256)
#define META_INTS   2048
// mi layout: [0]=np ; [8..168) plane base elem offsets (padded/clamped) ;
//            [168..168+1176) weight bytes packed 4 m/int, 8 ints/plane (zero padded)

// ---------------- setup: parallel, LDS-only (proven ~µs) ----------------
__global__ __launch_bounds__(256) void pfe_setup(
    const int* __restrict__ lidx, const int* __restrict__ hidx, int* __restrict__ mi)
{
    __shared__ unsigned char s_cl[M_DIM][16];
    __shared__ unsigned char s_ch[M_DIM][16];
    __shared__ int s_used[144];
    __shared__ int s_slot[144];
    const int t = threadIdx.x;
    for (int i = t; i < 1176; i += 256) mi[168 + i] = 0;   // zero weight region
    if (t < M_DIM) {
        for (int l = 0; l < L_DIM; ++l) s_cl[t][l] = 0;
        for (int h = 0; h < H_DIM; ++h) s_ch[t][h] = 0;
        for (int i = 0; i < NL; ++i) s_cl[t][lidx[t * NL + i]]++;
        for (int j = 0; j < NH; ++j) s_ch[t][hidx[t * NH + j]]++;
    }
    __syncthreads();
    if (t < 144) {
        const int l = t / H_DIM, h = t % H_DIM;
        int u = 0;
        for (int m = 0; m < M_DIM; ++m) u |= (s_cl[m][l] && s_ch[m][h]) ? 1 : 0;
        s_used[t] = u;
    }
    __syncthreads();
    if (t == 0) {
        int np = 0, lastb = 0;
        for (int k = 0; k < 144; ++k) {
            if (s_used[k]) {
                s_slot[k] = np;
                lastb = ((k / H_DIM) * (B_DIM * H_DIM) + (k % H_DIM)) * S2;
                mi[8 + np] = lastb;
                ++np;
            } else s_slot[k] = -1;
        }
        for (int p = np; p < 160; ++p) mi[8 + p] = lastb;   // clamp pads (safe loads)
        mi[0] = np;
    }
    __syncthreads();
    if (t < 144) {
        const int sl = s_slot[t];
        if (sl >= 0) {
            const int l = t / H_DIM, h = t % H_DIM;
            int wd[8] = {0, 0, 0, 0, 0, 0, 0, 0};
#pragma unroll
            for (int g = 0; g < 8; ++g) {
                int w = 0;
#pragma unroll
                for (int j = 0; j < 4; ++j) {
                    const int m = g * 4 + j;
                    w |= ((int)s_cl[m][l] * (int)s_ch[m][h]) << (8 * j);
                }
                wd[g] = w;
            }
            int* wp = mi + 168 + sl * 8;
#pragma unroll
            for (int g = 0; g < 8; ++g) wp[g] = wd[g];
        }
    }
}

// ---------------- main: 512 thr, float2/thread, 8-deep pipeline ----------
// thread = (b = t>>6, q = t&63) owns float2 at st=q*2. One wave = one b =
// one contiguous 512B segment per load instr (same DRAM granularity as R10).
// acc[32] float2 (64 VGPR) -> ~110 total -> 4 waves/SIMD (16/CU) = 2x R10.
__global__ __launch_bounds__(512, 4) void pfe_gather(
    const float* __restrict__ attn, const float* __restrict__ refs,
    const int* __restrict__ mi, float* __restrict__ part)
{
    __shared__ int s_pbase[160];
    __shared__ int s_ww[1176];
    __shared__ float s_x[8 * B_DIM * C];   // 32 KB exchange (8 m-slice)

    const int t = threadIdx.x;
    for (int i = t; i < 160; i += 512) s_pbase[i] = mi[8 + i];
    for (int i = t; i < 1176; i += 512) s_ww[i] = mi[168 + i];
    const int np8 = (mi[0] + 7) & ~7;
    __syncthreads();

    const int b = t >> 6, q = t & 63;
    const unsigned off0 = (unsigned)blockIdx.x * C;
    const unsigned fixoff = (unsigned)b * (unsigned)HS2 + off0 + (unsigned)q * 2u;

    float2 acc[M_DIM];
#pragma unroll
    for (int m = 0; m < M_DIM; ++m) acc[m] = make_float2(0.f, 0.f);

#define LD(P) (*reinterpret_cast<const float2*>(attn + (unsigned)s_pbase[P] + fixoff))

#define PROC_WORD(SW, G, V)                                             \
    if (SW) {                                                           \
        const float f0 = (float)((SW) & 255);                           \
        const float f1 = (float)(((SW) >> 8) & 255);                    \
        const float f2 = (float)(((SW) >> 16) & 255);                   \
        const float f3 = (float)(((SW) >> 24) & 255);                   \
        acc[4*(G)+0].x = fmaf(f0, (V).x, acc[4*(G)+0].x);               \
        acc[4*(G)+0].y = fmaf(f0, (V).y, acc[4*(G)+0].y);               \
        acc[4*(G)+1].x = fmaf(f1, (V).x, acc[4*(G)+1].x);               \
        acc[4*(G)+1].y = fmaf(f1, (V).y, acc[4*(G)+1].y);               \
        acc[4*(G)+2].x = fmaf(f2, (V).x, acc[4*(G)+2].x);               \
        acc[4*(G)+2].y = fmaf(f2, (V).y, acc[4*(G)+2].y);               \
        acc[4*(G)+3].x = fmaf(f3, (V).x, acc[4*(G)+3].x);               \
        acc[4*(G)+3].y = fmaf(f3, (V).y, acc[4*(G)+3].y);               \
    }

#define PROC_PLANE(P, V)                                                \
    {                                                                   \
        const int4 wa = *reinterpret_cast<const int4*>(s_ww + (P) * 8); \
        const int4 wb = *reinterpret_cast<const int4*>(s_ww + (P) * 8 + 4); \
        const int w0 = __builtin_amdgcn_readfirstlane(wa.x);            \
        const int w1 = __builtin_amdgcn_readfirstlane(wa.y);            \
        const int w2 = __builtin_amdgcn_readfirstlane(wa.z);            \
        const int w3 = __builtin_amdgcn_readfirstlane(wa.w);            \
        const int w4 = __builtin_amdgcn_readfirstlane(wb.x);            \
        const int w5 = __builtin_amdgcn_readfirstlane(wb.y);            \
        const int w6 = __builtin_amdgcn_readfirstlane(wb.z);            \
        const int w7 = __builtin_amdgcn_readfirstlane(wb.w);            \
        PROC_WORD(w0, 0, V) PROC_WORD(w1, 1, V)                         \
        PROC_WORD(w2, 2, V) PROC_WORD(w3, 3, V)                         \
        PROC_WORD(w4, 4, V) PROC_WORD(w5, 5, V)                         \
        PROC_WORD(w6, 6, V) PROC_WORD(w7, 7, V)                         \
    }

    // 8-deep register prefetch pipeline (bases clamped past np -> safe loads)
    float2 n0 = LD(0), n1 = LD(1), n2 = LD(2), n3 = LD(3),
           n4 = LD(4), n5 = LD(5), n6 = LD(6), n7 = LD(7);
    for (int p = 0; p < np8; p += 8) {
        const float2 c0 = n0, c1 = n1, c2 = n2, c3 = n3,
                     c4 = n4, c5 = n5, c6 = n6, c7 = n7;
        n0 = LD(p + 8);  n1 = LD(p + 9);  n2 = LD(p + 10); n3 = LD(p + 11);
        n4 = LD(p + 12); n5 = LD(p + 13); n6 = LD(p + 14); n7 = LD(p + 15);
        PROC_PLANE(p + 0, c0)
        PROC_PLANE(p + 1, c1)
        PROC_PLANE(p + 2, c2)
        PROC_PLANE(p + 3, c3)
        PROC_PLANE(p + 4, c4)
        PROC_PLANE(p + 5, c5)
        PROC_PLANE(p + 6, c6)
        PROC_PLANE(p + 7, c7)
    }
#undef PROC_PLANE
#undef PROC_WORD
#undef LD

    const float c12 = 1.0f / 12.0f;
    const int mm = t >> 6;   // wave index = stats m-within-slice

    // refs prefetch for slice 0 (issued while final plane loads drain)
    float2 rv_next = *reinterpret_cast<const float2*>(
        refs + (size_t)mm * S2 + off0 + (unsigned)q * 2u);

    // ---- stats: 4 slices of 8 m's through 32 KB LDS exchange ----
#pragma unroll
    for (int sl = 0; sl < 4; ++sl) {
        __syncthreads();   // previous slice's reads done
#pragma unroll
        for (int k = 0; k < 8; ++k) {
            const float2 a = acc[sl * 8 + k];
            float2 p;
            p.x = a.x * c12; p.y = a.y * c12;
            *reinterpret_cast<float2*>(&s_x[(k * B_DIM + b) * C + q * 2]) = p;
        }
        __syncthreads();   // slice data ready

        const int m = sl * 8 + mm;
        const float2 rv = rv_next;
        if (sl < 3) {
            rv_next = *reinterpret_cast<const float2*>(
                refs + (size_t)(m + 8) * S2 + off0 + (unsigned)q * 2u);
        }
        float2 x[B_DIM];
#pragma unroll
        for (int bb = 0; bb < B_DIM; ++bb)
            x[bb] = *reinterpret_cast<const float2*>(&s_x[(mm * B_DIM + bb) * C + q * 2]);
        float2 mu = make_float2(0.f, 0.f);
#pragma unroll
        for (int bb = 0; bb < B_DIM; ++bb) { mu.x += x[bb].x; mu.y += x[bb].y; }
        mu.x *= 0.125f; mu.y *= 0.125f;
        float2 ss = make_float2(0.f, 0.f);
#pragma unroll
        for (int bb = 0; bb < B_DIM; ++bb) {
            const float dx = x[bb].x - mu.x, dy = x[bb].y - mu.y;
            ss.x = fmaf(dx, dx, ss.x); ss.y = fmaf(dy, dy, ss.y);
        }
        const float c7 = 1.0f / 7.0f;
        float2 inv;
        inv.x = 1.0f / fmaxf(sqrtf(ss.x * c7), 1e-8f);
        inv.y = 1.0f / fmaxf(sqrtf(ss.y * c7), 1e-8f);

        float zs[B_DIM];
#pragma unroll
        for (int bb = 0; bb < B_DIM; ++bb) {
            const float zx = (x[bb].x - rv.x) * inv.x;
            const float zy = (x[bb].y - rv.y) * inv.y;
            zs[bb] = fmaf(zx, zx, zy * zy);
        }
        // reduce over q (full 64-lane wave)
#pragma unroll
        for (int bb = 0; bb < B_DIM; ++bb) {
            float v = zs[bb];
            v += __shfl_xor(v, 1);
            v += __shfl_xor(v, 2);
            v += __shfl_xor(v, 4);
            v += __shfl_xor(v, 8);
            v += __shfl_xor(v, 16);
            v += __shfl_xor(v, 32);
            zs[bb] = v;
        }
        if (q == 0) {
            float* pp = part + blockIdx.x * 256 + m * B_DIM;
            *reinterpret_cast<float4*>(pp) =
                make_float4(zs[0], zs[1], zs[2], zs[3]);
            *reinterpret_cast<float4*>(pp + 4) =
                make_float4(zs[4], zs[5], zs[6], zs[7]);
        }
    }
}

// ---------------- deterministic two-stage reduction ----------------
__global__ __launch_bounds__(256) void pfe_red1(
    const float* __restrict__ part, float* __restrict__ mid)
{
    const int t = threadIdx.x;
    const int c0 = blockIdx.x * RED1;
    float s = 0.f;
#pragma unroll
    for (int i = 0; i < RED1; ++i) s += part[(c0 + i) * 256 + t];
    mid[blockIdx.x * 256 + t] = s;
}

__global__ __launch_bounds__(256) void pfe_red2(
    const float* __restrict__ mid, float* __restrict__ out)
{
    const int t = threadIdx.x;          // t = m*8 + b
    float s = 0.f;
#pragma unroll
    for (int i = 0; i < NRED1; ++i) s += mid[i * 256 + t];
    out[(t & 7) * M_DIM + (t >> 3)] = s * (1.0f / (float)S2);
}

// ---------------- fallback path (tiny ws): per-(m,chunk) atomic ----------------
__global__ void pfe_zero(float* __restrict__ out) {
    if (threadIdx.x < M_DIM * B_DIM) out[threadIdx.x] = 0.f;
}

#define FCH 512
#define FNCH (S2 / FCH)
__global__ __launch_bounds__(128) void pfe_fallback(
    const float* __restrict__ attn, const float* __restrict__ refs,
    const int* __restrict__ lidx, const int* __restrict__ hidx,
    float* __restrict__ out)
{
    const int p = blockIdx.x;
    const int m = p & (M_DIM - 1);
    const int chunk = p >> 5;
    const int tid = threadIdx.x;
    const unsigned st = (unsigned)chunk * FCH + (unsigned)tid * 4;

    __shared__ int   s_mk[NL * NH];
    __shared__ float s_mw[NL * NH];
    __shared__ int   s_nm;
    __shared__ float s_red[2 * B_DIM];

    if (tid == 0) {
        int keys[NL * NH];
        for (int i = 0; i < NL; ++i) {
            const int l = lidx[m * NL + i];
            for (int j = 0; j < NH; ++j) keys[i * NH + j] = l * 16 + hidx[m * NH + j];
        }
        for (int i = 1; i < NL * NH; ++i) {
            const int k = keys[i]; int j = i - 1;
            for (; j >= 0 && keys[j] > k; --j) keys[j + 1] = keys[j];
            keys[j + 1] = k;
        }
        int nm = 0;
        for (int i = 0; i < NL * NH; ++i) {
            if (nm > 0 && s_mk[nm - 1] == keys[i]) s_mw[nm - 1] += 1.0f;
            else { s_mk[nm] = keys[i]; s_mw[nm] = 1.0f; ++nm; }
        }
        s_nm = nm;
    }
    __syncthreads();

    const float4 r = *reinterpret_cast<const float4*>(refs + (unsigned)m * (unsigned)S2 + st);
    float4 acc[B_DIM];
    for (int bb = 0; bb < B_DIM; ++bb) acc[bb] = make_float4(0.f, 0.f, 0.f, 0.f);
    const int nm = s_nm;
    for (int e = 0; e < nm; ++e) {
        const int k = s_mk[e]; const float w = s_mw[e];
        const int l = k >> 4, h = k & 15;
        const unsigned base = (unsigned)(l * (B_DIM * H_DIM) + h) * (unsigned)S2 + st;
        for (int bb = 0; bb < B_DIM; ++bb) {
            const float4 v = *reinterpret_cast<const float4*>(
                attn + base + (unsigned)bb * (unsigned)HS2);
            acc[bb].x = fmaf(w, v.x, acc[bb].x); acc[bb].y = fmaf(w, v.y, acc[bb].y);
            acc[bb].z = fmaf(w, v.z, acc[bb].z); acc[bb].w = fmaf(w, v.w, acc[bb].w);
        }
    }
    const float c12 = 1.0f / 12.0f;
    float4 pmv[B_DIM];
    for (int bb = 0; bb < B_DIM; ++bb) {
        pmv[bb].x = acc[bb].x * c12; pmv[bb].y = acc[bb].y * c12;
        pmv[bb].z = acc[bb].z * c12; pmv[bb].w = acc[bb].w * c12;
    }
    float4 mu = make_float4(0.f, 0.f, 0.f, 0.f);
    for (int bb = 0; bb < B_DIM; ++bb) {
        mu.x += pmv[bb].x; mu.y += pmv[bb].y; mu.z += pmv[bb].z; mu.w += pmv[bb].w;
    }
    mu.x *= 0.125f; mu.y *= 0.125f; mu.z *= 0.125f; mu.w *= 0.125f;
    float4 ss = make_float4(0.f, 0.f, 0.f, 0.f);
    for (int bb = 0; bb < B_DIM; ++bb) {
        const float dx = pmv[bb].x - mu.x, dy = pmv[bb].y - mu.y,
                    dz = pmv[bb].z - mu.z, dw = pmv[bb].w - mu.w;
        ss.x += dx * dx; ss.y += dy * dy; ss.z += dz * dz; ss.w += dw * dw;
    }
    const float c7 = 1.0f / 7.0f;
    float4 inv;
    inv.x = 1.0f / fmaxf(sqrtf(ss.x * c7), 1e-8f);
    inv.y = 1.0f / fmaxf(sqrtf(ss.y * c7), 1e-8f);
    inv.z = 1.0f / fmaxf(sqrtf(ss.z * c7), 1e-8f);
    inv.w = 1.0f / fmaxf(sqrtf(ss.w * c7), 1e-8f);
    float s[B_DIM];
    for (int bb = 0; bb < B_DIM; ++bb) {
        const float zx = (pmv[bb].x - r.x) * inv.x;
        const float zy = (pmv[bb].y - r.y) * inv.y;
        const float zz = (pmv[bb].z - r.z) * inv.z;
        const float zw = (pmv[bb].w - r.w) * inv.w;
        s[bb] = zx * zx + zy * zy + zz * zz + zw * zw;
    }
    for (int bb = 0; bb < B_DIM; ++bb) {
        float v = s[bb];
        for (int off = 32; off > 0; off >>= 1) v += __shfl_down(v, off);
        s[bb] = v;
    }
    const int lane = tid & 63, wave = tid >> 6;
    if (lane == 0) for (int bb = 0; bb < B_DIM; ++bb) s_red[wave * B_DIM + bb] = s[bb];
    __syncthreads();
    if (tid < B_DIM) {
        const float tot = (s_red[tid] + s_red[B_DIM + tid]) * (1.0f / (float)S2);
        atomicAdd(&out[tid * M_DIM + m], tot);
    }
}

extern "C" void kernel_launch(void* const* d_in, const int* in_sizes, int n_in,
                              void* d_out, int out_size, void* d_ws, size_t ws_size,
                              hipStream_t stream) {
    const float* attn = (const float*)d_in[0];
    const float* refs = (const float*)d_in[1];
    const int*   lidx = (const int*)d_in[2];
    const int*   hidx = (const int*)d_in[3];
    float* out = (float*)d_out;

    const size_t ws_needed =
        (size_t)(PART_FLOATS + MID_FLOATS + META_INTS) * sizeof(float);

    if (ws_size >= ws_needed) {
        float* part = (float*)d_ws;
        float* mid  = part + PART_FLOATS;
        int*   mi   = (int*)(mid + MID_FLOATS);
        pfe_setup<<<1, 256, 0, stream>>>(lidx, hidx, mi);
        pfe_gather<<<NCH, 512, 0, stream>>>(attn, refs, mi, part);
        pfe_red1<<<NRED1, 256, 0, stream>>>(part, mid);
        pfe_red2<<<1, 256, 0, stream>>>(mid, out);
    } else {
        pfe_zero<<<1, 256, 0, stream>>>(out);
        pfe_fallback<<<FNCH * M_DIM, 128, 0, stream>>>(attn, refs, lidx, hidx, out);
    }
}

// Round 13
// 150.028 us; speedup vs baseline: 1.1068x; 1.1019x over previous
//
#include <hip/hip_runtime.h>

// Problem constants (from reference setup_inputs)
#define L_DIM 12
#define B_DIM 8
#define H_DIM 12
#define S2    147456              // 384*384
#define M_DIM 32
#define NL 3
#define NH 4
#define HS2   (H_DIM * S2)        // batch stride in attn elements

// design: global->register plane streaming, no LDS staging, no barriers
#define C      128                // st elements per block (chunk)
#define NCH    (S2 / C)           // 1152 blocks
#define RED1   32                 // chunks per red1 block
#define NRED1  (NCH / RED1)       // 36

#define PART_FLOATS (NCH * 256)
#define MID_FLOATS  (NRED1 * 256)
#define META_INTS   2048
// mi layout: [0]=np ; [8..168) plane base elem offsets (padded/clamped) ;
//            [168..168+1176) weight bytes packed 4 m/int, 8 ints/plane (zero padded)

// ---------------- setup: FULLY parallel (R13: removed ~25us serial scan) -----
__global__ __launch_bounds__(256) void pfe_setup(
    const int* __restrict__ lidx, const int* __restrict__ hidx, int* __restrict__ mi)
{
    __shared__ unsigned char s_cl[M_DIM][16];
    __shared__ unsigned char s_ch[M_DIM][16];
    __shared__ int s_used[144];
    __shared__ int s_slot[144];
    __shared__ int s_npv;
    __shared__ int s_fb;
    const int t = threadIdx.x;
    for (int i = t; i < 1176; i += 256) mi[168 + i] = 0;   // zero weight region
    if (t < M_DIM) {
        for (int l = 0; l < L_DIM; ++l) s_cl[t][l] = 0;
        for (int h = 0; h < H_DIM; ++h) s_ch[t][h] = 0;
        for (int i = 0; i < NL; ++i) s_cl[t][lidx[t * NL + i]]++;
        for (int j = 0; j < NH; ++j) s_ch[t][hidx[t * NH + j]]++;
    }
    __syncthreads();
    if (t < 144) {
        const int l = t / H_DIM, h = t % H_DIM;
        int u = 0;
        for (int m = 0; m < M_DIM; ++m) u |= (s_cl[m][l] && s_ch[m][h]) ? 1 : 0;
        s_used[t] = u;
    }
    __syncthreads();
    // parallel prefix scan: slot[t] = #used before t (LDS reads are broadcast)
    if (t < 144) {
        int c = 0;
        for (int j = 0; j < t; ++j) c += s_used[j];
        const int base = ((t / H_DIM) * (B_DIM * H_DIM) + (t % H_DIM)) * S2;
        if (s_used[t]) {
            s_slot[t] = c;
            mi[8 + c] = base;
            if (c == 0) s_fb = base;
        } else s_slot[t] = -1;
        if (t == 143) s_npv = c + s_used[143];
    }
    __syncthreads();
    const int np = s_npv;
    if (t == 0) mi[0] = np;
    if (t >= np && t < 160) mi[8 + t] = s_fb;   // clamp pads (safe dummy loads)
    if (t < 144) {
        const int sl = s_slot[t];
        if (sl >= 0) {
            const int l = t / H_DIM, h = t % H_DIM;
#pragma unroll
            for (int g = 0; g < 8; ++g) {
                int w = 0;
#pragma unroll
                for (int j = 0; j < 4; ++j) {
                    const int m = g * 4 + j;
                    w |= ((int)s_cl[m][l] * (int)s_ch[m][h]) << (8 * j);
                }
                mi[168 + sl * 8 + g] = w;
            }
        }
    }
}

// ---------------- main: global->register streaming, register scatter ----------
// 256 threads = 4 waves. thread = (b = t>>5, q = t&31) owns float4 at st=q*4.
// acc[32] float4 in VGPRs (ALL indices compile-time static — R9 showed that
// losing this demotes acc to scratch for a 6x slowdown). No barriers in the
// gather loop. Byte-identical to R10's gather (best measured: 161.8 us).
__global__ __launch_bounds__(256) void pfe_gather(
    const float* __restrict__ attn, const float* __restrict__ refs,
    const int* __restrict__ mi, float* __restrict__ part)
{
    __shared__ int s_pbase[160];
    __shared__ int s_ww[1176];
    __shared__ float s_x[8 * B_DIM * C];   // 32 KB exchange (8 m-slice)

    const int t = threadIdx.x;
    for (int i = t; i < 160; i += 256) s_pbase[i] = mi[8 + i];
    for (int i = t; i < 1176; i += 256) s_ww[i] = mi[168 + i];
    const int np4 = (mi[0] + 3) & ~3;
    __syncthreads();

    const int b = t >> 5, q = t & 31;
    const unsigned off0 = (unsigned)blockIdx.x * C;
    const unsigned fixoff = (unsigned)b * (unsigned)HS2 + off0 + (unsigned)q * 4u;

    float4 acc[M_DIM];
#pragma unroll
    for (int m = 0; m < M_DIM; ++m) acc[m] = make_float4(0.f, 0.f, 0.f, 0.f);

#define LD(P) (*reinterpret_cast<const float4*>(attn + (unsigned)s_pbase[P] + fixoff))

#define PROC_WORD(SW, G, V)                                             \
    if (SW) {                                                           \
        const float f0 = (float)((SW) & 255);                           \
        const float f1 = (float)(((SW) >> 8) & 255);                    \
        const float f2 = (float)(((SW) >> 16) & 255);                   \
        const float f3 = (float)(((SW) >> 24) & 255);                   \
        acc[4*(G)+0].x = fmaf(f0, (V).x, acc[4*(G)+0].x);               \
        acc[4*(G)+0].y = fmaf(f0, (V).y, acc[4*(G)+0].y);               \
        acc[4*(G)+0].z = fmaf(f0, (V).z, acc[4*(G)+0].z);               \
        acc[4*(G)+0].w = fmaf(f0, (V).w, acc[4*(G)+0].w);               \
        acc[4*(G)+1].x = fmaf(f1, (V).x, acc[4*(G)+1].x);               \
        acc[4*(G)+1].y = fmaf(f1, (V).y, acc[4*(G)+1].y);               \
        acc[4*(G)+1].z = fmaf(f1, (V).z, acc[4*(G)+1].z);               \
        acc[4*(G)+1].w = fmaf(f1, (V).w, acc[4*(G)+1].w);               \
        acc[4*(G)+2].x = fmaf(f2, (V).x, acc[4*(G)+2].x);               \
        acc[4*(G)+2].y = fmaf(f2, (V).y, acc[4*(G)+2].y);               \
        acc[4*(G)+2].z = fmaf(f2, (V).z, acc[4*(G)+2].z);               \
        acc[4*(G)+2].w = fmaf(f2, (V).w, acc[4*(G)+2].w);               \
        acc[4*(G)+3].x = fmaf(f3, (V).x, acc[4*(G)+3].x);               \
        acc[4*(G)+3].y = fmaf(f3, (V).y, acc[4*(G)+3].y);               \
        acc[4*(G)+3].z = fmaf(f3, (V).z, acc[4*(G)+3].z);               \
        acc[4*(G)+3].w = fmaf(f3, (V).w, acc[4*(G)+3].w);               \
    }

#define PROC_PLANE(P, V)                                                \
    {                                                                   \
        const int4 wa = *reinterpret_cast<const int4*>(s_ww + (P) * 8); \
        const int4 wb = *reinterpret_cast<const int4*>(s_ww + (P) * 8 + 4); \
        const int w0 = __builtin_amdgcn_readfirstlane(wa.x);            \
        const int w1 = __builtin_amdgcn_readfirstlane(wa.y);            \
        const int w2 = __builtin_amdgcn_readfirstlane(wa.z);            \
        const int w3 = __builtin_amdgcn_readfirstlane(wa.w);            \
        const int w4 = __builtin_amdgcn_readfirstlane(wb.x);            \
        const int w5 = __builtin_amdgcn_readfirstlane(wb.y);            \
        const int w6 = __builtin_amdgcn_readfirstlane(wb.z);            \
        const int w7 = __builtin_amdgcn_readfirstlane(wb.w);            \
        PROC_WORD(w0, 0, V) PROC_WORD(w1, 1, V)                         \
        PROC_WORD(w2, 2, V) PROC_WORD(w3, 3, V)                         \
        PROC_WORD(w4, 4, V) PROC_WORD(w5, 5, V)                         \
        PROC_WORD(w6, 6, V) PROC_WORD(w7, 7, V)                         \
    }

    // 4-deep register prefetch pipeline (bases clamped past np -> safe loads)
    float4 n0 = LD(0), n1 = LD(1), n2 = LD(2), n3 = LD(3);
    for (int p = 0; p < np4; p += 4) {
        const float4 c0 = n0, c1 = n1, c2 = n2, c3 = n3;
        n0 = LD(p + 4); n1 = LD(p + 5); n2 = LD(p + 6); n3 = LD(p + 7);
        PROC_PLANE(p + 0, c0)
        PROC_PLANE(p + 1, c1)
        PROC_PLANE(p + 2, c2)
        PROC_PLANE(p + 3, c3)
    }
#undef PROC_PLANE
#undef PROC_WORD
#undef LD

    const float c12 = 1.0f / 12.0f;
    const int mm = t >> 5;   // 0..7 within slice (half-wave uniform)

    // refs prefetch for slice 0 (issued while final plane loads drain)
    float4 rv_next = *reinterpret_cast<const float4*>(
        refs + (size_t)mm * S2 + off0 + (unsigned)q * 4u);

    // ---- stats: 4 slices of 8 m's through 32 KB LDS exchange ----
#pragma unroll
    for (int sl = 0; sl < 4; ++sl) {
        __syncthreads();   // previous slice's reads done
#pragma unroll
        for (int k = 0; k < 8; ++k) {
            const float4 a = acc[sl * 8 + k];
            float4 p;
            p.x = a.x * c12; p.y = a.y * c12; p.z = a.z * c12; p.w = a.w * c12;
            *reinterpret_cast<float4*>(&s_x[(k * B_DIM + b) * C + q * 4]) = p;
        }
        __syncthreads();   // slice data ready

        const int m = sl * 8 + mm;
        const float4 rv = rv_next;
        if (sl < 3) {
            rv_next = *reinterpret_cast<const float4*>(
                refs + (size_t)(m + 8) * S2 + off0 + (unsigned)q * 4u);
        }
        float4 x[B_DIM];
#pragma unroll
        for (int bb = 0; bb < B_DIM; ++bb)
            x[bb] = *reinterpret_cast<const float4*>(&s_x[(mm * B_DIM + bb) * C + q * 4]);
        float4 mu = make_float4(0.f, 0.f, 0.f, 0.f);
#pragma unroll
        for (int bb = 0; bb < B_DIM; ++bb) {
            mu.x += x[bb].x; mu.y += x[bb].y; mu.z += x[bb].z; mu.w += x[bb].w;
        }
        mu.x *= 0.125f; mu.y *= 0.125f; mu.z *= 0.125f; mu.w *= 0.125f;
        float4 ss = make_float4(0.f, 0.f, 0.f, 0.f);
#pragma unroll
        for (int bb = 0; bb < B_DIM; ++bb) {
            const float dx = x[bb].x - mu.x, dy = x[bb].y - mu.y,
                        dz = x[bb].z - mu.z, dw = x[bb].w - mu.w;
            ss.x = fmaf(dx, dx, ss.x); ss.y = fmaf(dy, dy, ss.y);
            ss.z = fmaf(dz, dz, ss.z); ss.w = fmaf(dw, dw, ss.w);
        }
        const float c7 = 1.0f / 7.0f;
        float4 inv;
        inv.x = 1.0f / fmaxf(sqrtf(ss.x * c7), 1e-8f);
        inv.y = 1.0f / fmaxf(sqrtf(ss.y * c7), 1e-8f);
        inv.z = 1.0f / fmaxf(sqrtf(ss.z * c7), 1e-8f);
        inv.w = 1.0f / fmaxf(sqrtf(ss.w * c7), 1e-8f);

        float zs[B_DIM];
#pragma unroll
        for (int bb = 0; bb < B_DIM; ++bb) {
            const float zx = (x[bb].x - rv.x) * inv.x;
            const float zy = (x[bb].y - rv.y) * inv.y;
            const float zz = (x[bb].z - rv.z) * inv.z;
            const float zw = (x[bb].w - rv.w) * inv.w;
            zs[bb] = fmaf(zx, zx, fmaf(zy, zy, fmaf(zz, zz, zw * zw)));
        }
        // reduce over q (lane bits 0..4, stays within 32-lane half-wave)
#pragma unroll
        for (int bb = 0; bb < B_DIM; ++bb) {
            float v = zs[bb];
            v += __shfl_xor(v, 1);
            v += __shfl_xor(v, 2);
            v += __shfl_xor(v, 4);
            v += __shfl_xor(v, 8);
            v += __shfl_xor(v, 16);
            zs[bb] = v;
        }
        if (q == 0) {
            float* pp = part + blockIdx.x * 256 + m * B_DIM;
            *reinterpret_cast<float4*>(pp) =
                make_float4(zs[0], zs[1], zs[2], zs[3]);
            *reinterpret_cast<float4*>(pp + 4) =
                make_float4(zs[4], zs[5], zs[6], zs[7]);
        }
    }
}

// ---------------- deterministic two-stage reduction ----------------
__global__ __launch_bounds__(256) void pfe_red1(
    const float* __restrict__ part, float* __restrict__ mid)
{
    const int t = threadIdx.x;
    const int c0 = blockIdx.x * RED1;
    float s = 0.f;
#pragma unroll
    for (int i = 0; i < RED1; ++i) s += part[(c0 + i) * 256 + t];
    mid[blockIdx.x * 256 + t] = s;
}

__global__ __launch_bounds__(256) void pfe_red2(
    const float* __restrict__ mid, float* __restrict__ out)
{
    const int t = threadIdx.x;          // t = m*8 + b
    float s = 0.f;
#pragma unroll
    for (int i = 0; i < NRED1; ++i) s += mid[i * 256 + t];
    out[(t & 7) * M_DIM + (t >> 3)] = s * (1.0f / (float)S2);
}

// ---------------- fallback path (tiny ws): per-(m,chunk) atomic ----------------
__global__ void pfe_zero(float* __restrict__ out) {
    if (threadIdx.x < M_DIM * B_DIM) out[threadIdx.x] = 0.f;
}

#define FCH 512
#define FNCH (S2 / FCH)
__global__ __launch_bounds__(128) void pfe_fallback(
    const float* __restrict__ attn, const float* __restrict__ refs,
    const int* __restrict__ lidx, const int* __restrict__ hidx,
    float* __restrict__ out)
{
    const int p = blockIdx.x;
    const int m = p & (M_DIM - 1);
    const int chunk = p >> 5;
    const int tid = threadIdx.x;
    const unsigned st = (unsigned)chunk * FCH + (unsigned)tid * 4;

    __shared__ int   s_mk[NL * NH];
    __shared__ float s_mw[NL * NH];
    __shared__ int   s_nm;
    __shared__ float s_red[2 * B_DIM];

    if (tid == 0) {
        int keys[NL * NH];
        for (int i = 0; i < NL; ++i) {
            const int l = lidx[m * NL + i];
            for (int j = 0; j < NH; ++j) keys[i * NH + j] = l * 16 + hidx[m * NH + j];
        }
        for (int i = 1; i < NL * NH; ++i) {
            const int k = keys[i]; int j = i - 1;
            for (; j >= 0 && keys[j] > k; --j) keys[j + 1] = keys[j];
            keys[j + 1] = k;
        }
        int nm = 0;
        for (int i = 0; i < NL * NH; ++i) {
            if (nm > 0 && s_mk[nm - 1] == keys[i]) s_mw[nm - 1] += 1.0f;
            else { s_mk[nm] = keys[i]; s_mw[nm] = 1.0f; ++nm; }
        }
        s_nm = nm;
    }
    __syncthreads();

    const float4 r = *reinterpret_cast<const float4*>(refs + (unsigned)m * (unsigned)S2 + st);
    float4 acc[B_DIM];
    for (int bb = 0; bb < B_DIM; ++bb) acc[bb] = make_float4(0.f, 0.f, 0.f, 0.f);
    const int nm = s_nm;
    for (int e = 0; e < nm; ++e) {
        const int k = s_mk[e]; const float w = s_mw[e];
        const int l = k >> 4, h = k & 15;
        const unsigned base = (unsigned)(l * (B_DIM * H_DIM) + h) * (unsigned)S2 + st;
        for (int bb = 0; bb < B_DIM; ++bb) {
            const float4 v = *reinterpret_cast<const float4*>(
                attn + base + (unsigned)bb * (unsigned)HS2);
            acc[bb].x = fmaf(w, v.x, acc[bb].x); acc[bb].y = fmaf(w, v.y, acc[bb].y);
            acc[bb].z = fmaf(w, v.z, acc[bb].z); acc[bb].w = fmaf(w, v.w, acc[bb].w);
        }
    }
    const float c12 = 1.0f / 12.0f;
    float4 pmv[B_DIM];
    for (int bb = 0; bb < B_DIM; ++bb) {
        pmv[bb].x = acc[bb].x * c12; pmv[bb].y = acc[bb].y * c12;
        pmv[bb].z = acc[bb].z * c12; pmv[bb].w = acc[bb].w * c12;
    }
    float4 mu = make_float4(0.f, 0.f, 0.f, 0.f);
    for (int bb = 0; bb < B_DIM; ++bb) {
        mu.x += pmv[bb].x; mu.y += pmv[bb].y; mu.z += pmv[bb].z; mu.w += pmv[bb].w;
    }
    mu.x *= 0.125f; mu.y *= 0.125f; mu.z *= 0.125f; mu.w *= 0.125f;
    float4 ss = make_float4(0.f, 0.f, 0.f, 0.f);
    for (int bb = 0; bb < B_DIM; ++bb) {
        const float dx = pmv[bb].x - mu.x, dy = pmv[bb].y - mu.y,
                    dz = pmv[bb].z - mu.z, dw = pmv[bb].w - mu.w;
        ss.x += dx * dx; ss.y += dy * dy; ss.z += dz * dz; ss.w += dw * dw;
    }
    const float c7 = 1.0f / 7.0f;
    float4 inv;
    inv.x = 1.0f / fmaxf(sqrtf(ss.x * c7), 1e-8f);
    inv.y = 1.0f / fmaxf(sqrtf(ss.y * c7), 1e-8f);
    inv.z = 1.0f / fmaxf(sqrtf(ss.z * c7), 1e-8f);
    inv.w = 1.0f / fmaxf(sqrtf(ss.w * c7), 1e-8f);
    float s[B_DIM];
    for (int bb = 0; bb < B_DIM; ++bb) {
        const float zx = (pmv[bb].x - r.x) * inv.x;
        const float zy = (pmv[bb].y - r.y) * inv.y;
        const float zz = (pmv[bb].z - r.z) * inv.z;
        const float zw = (pmv[bb].w - r.w) * inv.w;
        s[bb] = zx * zx + zy * zy + zz * zz + zw * zw;
    }
    for (int bb = 0; bb < B_DIM; ++bb) {
        float v = s[bb];
        for (int off = 32; off > 0; off >>= 1) v += __shfl_down(v, off);
        s[bb] = v;
    }
    const int lane = tid & 63, wave = tid >> 6;
    if (lane == 0) for (int bb = 0; bb < B_DIM; ++bb) s_red[wave * B_DIM + bb] = s[bb];
    __syncthreads();
    if (tid < B_DIM) {
        const float tot = (s_red[tid] + s_red[B_DIM + tid]) * (1.0f / (float)S2);
        atomicAdd(&out[tid * M_DIM + m], tot);
    }
}

extern "C" void kernel_launch(void* const* d_in, const int* in_sizes, int n_in,
                              void* d_out, int out_size, void* d_ws, size_t ws_size,
                              hipStream_t stream) {
    const float* attn = (const float*)d_in[0];
    const float* refs = (const float*)d_in[1];
    const int*   lidx = (const int*)d_in[2];
    const int*   hidx = (const int*)d_in[3];
    float* out = (float*)d_out;

    const size_t ws_needed =
        (size_t)(PART_FLOATS + MID_FLOATS + META_INTS) * sizeof(float);

    if (ws_size >= ws_needed) {
        float* part = (float*)d_ws;
        float* mid  = part + PART_FLOATS;
        int*   mi   = (int*)(mid + MID_FLOATS);
        pfe_setup<<<1, 256, 0, stream>>>(lidx, hidx, mi);
        pfe_gather<<<NCH, 256, 0, stream>>>(attn, refs, mi, part);
        pfe_red1<<<NRED1, 256, 0, stream>>>(part, mid);
        pfe_red2<<<1, 256, 0, stream>>>(mid, out);
    } else {
        pfe_zero<<<1, 256, 0, stream>>>(out);
        pfe_fallback<<<FNCH * M_DIM, 128, 0, stream>>>(attn, refs, lidx, hidx, out);
    }
}